// Round 2
// baseline (290.283 us; speedup 1.0000x reference)
//
#include <hip/hip_runtime.h>
#include <hip/hip_bf16.h>
#include <stdint.h>

#define M_TOT 8192
#define DIN   1024
#define DEXP  1024
#define NEXP  8

#define BM 256
#define BN 128
#define BK 64
#define NT 128            // 8 experts * 16 K-tiles
#define TPE 16            // K-tiles per expert
#define SLOT_E 24576      // elems per LDS slot: A 16384 + B 8192

typedef __attribute__((ext_vector_type(8))) short bf16x8;
typedef __attribute__((ext_vector_type(4))) float f32x4;
typedef __attribute__((ext_vector_type(8))) unsigned short us8;

typedef __attribute__((address_space(1))) void* as1vp;
typedef __attribute__((address_space(3))) void* as3vp;

__device__ __forceinline__ unsigned short f2bf(float f) {
    union { float f; unsigned u; } v; v.f = f;
    return (unsigned short)((v.u + 0x7fffu + ((v.u >> 16) & 1u)) >> 16);
}

__device__ __forceinline__ void gl_lds16(const unsigned short* g, unsigned short* l) {
    __builtin_amdgcn_global_load_lds((as1vp)g, (as3vp)l, 16, 0, 0);
}

// ---------------- x fp32 -> bf16 ----------------
__global__ __launch_bounds__(256) void cvt_x_k(const float* __restrict__ in,
                                               unsigned short* __restrict__ out, int n8) {
    int i = blockIdx.x * 256 + threadIdx.x;
    int stride = gridDim.x * 256;
    for (; i < n8; i += stride) {
        const float4* p = (const float4*)in + (size_t)i * 2;
        float4 a = p[0], b = p[1];
        us8 o;
        o[0] = f2bf(a.x); o[1] = f2bf(a.y); o[2] = f2bf(a.z); o[3] = f2bf(a.w);
        o[4] = f2bf(b.x); o[5] = f2bf(b.y); o[6] = f2bf(b.z); o[7] = f2bf(b.w);
        *(us8*)(out + (size_t)i * 8) = o;
    }
}

// ------- We (n, din, dexp) fp32 -> Wt (n, dexp, din) bf16, tiled transpose -------
__global__ __launch_bounds__(256) void cvt_w_k(const float* __restrict__ We,
                                               unsigned short* __restrict__ Wt) {
    __shared__ float tile[64][65];
    int n  = blockIdx.z;
    int k0 = blockIdx.y * 64;   // din index
    int j0 = blockIdx.x * 64;   // dexp index
    int t  = threadIdx.x;
    int tr = t >> 6, tc = t & 63;
    const float* src = We + (size_t)n * DIN * DEXP;
    #pragma unroll
    for (int rr = 0; rr < 16; ++rr) {
        int r = rr * 4 + tr;
        tile[r][tc] = src[(size_t)(k0 + r) * DEXP + j0 + tc];
    }
    __syncthreads();
    unsigned short* dst = Wt + (size_t)n * DEXP * DIN;
    #pragma unroll
    for (int rr = 0; rr < 16; ++rr) {
        int r = rr * 4 + tr;
        dst[(size_t)(j0 + r) * DIN + k0 + tc] = f2bf(tile[tc][r]);
    }
}

// ---------------- gate = softmax(x @ Wg + bg) ----------------
__global__ __launch_bounds__(256) void gate_k(const float* __restrict__ x,
                                              const float* __restrict__ Wg,
                                              const float* __restrict__ bg,
                                              float* __restrict__ gate) {
    __shared__ float wgt[NEXP][DIN];
    int t = threadIdx.x;
    for (int idx = t; idx < DIN * NEXP; idx += 256)
        wgt[idx & 7][idx >> 3] = Wg[idx];
    __syncthreads();
    int wid = t >> 6, lane = t & 63;
    for (int m = blockIdx.x * 4 + wid; m < M_TOT; m += gridDim.x * 4) {
        const float* xr = x + (size_t)m * DIN;
        float acc[NEXP];
        #pragma unroll
        for (int n = 0; n < NEXP; ++n) acc[n] = 0.f;
        for (int i = 0; i < DIN / 64; ++i) {
            int d = i * 64 + lane;
            float xv = xr[d];
            #pragma unroll
            for (int n = 0; n < NEXP; ++n) acc[n] = fmaf(xv, wgt[n][d], acc[n]);
        }
        #pragma unroll
        for (int n = 0; n < NEXP; ++n) {
            #pragma unroll
            for (int off = 32; off; off >>= 1) acc[n] += __shfl_xor(acc[n], off);
            acc[n] += bg[n];
        }
        float mx = acc[0];
        #pragma unroll
        for (int n = 1; n < NEXP; ++n) mx = fmaxf(mx, acc[n]);
        float s = 0.f, e[NEXP];
        #pragma unroll
        for (int n = 0; n < NEXP; ++n) { e[n] = __expf(acc[n] - mx); s += e[n]; }
        float inv = 1.f / s;
        if (lane < NEXP) gate[(size_t)m * NEXP + lane] = e[lane] * inv;
    }
}

// ---------------- fused MoE GEMM: counted-vmcnt 4-phase pipeline ----------------
// out[m,j] = sum_e gate[m,e] * relu( (Xb @ Wt[e]^T)[m,j] + be[e,j] )
__global__ __launch_bounds__(512, 2) void moe_k(const unsigned short* __restrict__ Xb,
                                                const unsigned short* __restrict__ Wt,
                                                const float* __restrict__ gate,
                                                const float* __restrict__ be,
                                                float* __restrict__ out) {
    // 3 rotating slots: A [256][64] bf16 (elems 0..16383, rows 0-127 then 128-255),
    //                   B [128][64] bf16 (elems 16384..24575). 144 KiB total.
    __shared__ __align__(16) unsigned short lds[3 * SLOT_E];

    const int t    = threadIdx.x;
    const int lane = t & 63;
    const int wv   = t >> 6;            // 0..7
    const int wm   = wv >> 1;           // 0..3 (M)
    const int wn   = wv & 1;            // 0..1 (N)
    const int l16  = lane & 15;
    const int lk   = lane >> 4;

    // bijective XCD swizzle (grid 256, %8==0)
    const int b   = blockIdx.x;
    const int lg  = (b & 7) * 32 + (b >> 3);
    const int brow = (lg >> 3) * BM;
    const int bcol = (lg & 7) * BN;

    // staging source precompute: chunk c1 = t (row=t>>3, physcol=t&7), c2 = c1+512 (row+64)
    const int r1  = t >> 3;
    const int cp1 = t & 7;
    const int srcOff = r1 * DIN + ((cp1 ^ (r1 & 7)) * 8);   // inverse-swizzled source col
    const unsigned short* Abase  = Xb + (size_t)brow * DIN + srcOff;
    const unsigned short* Bbase0 = Wt + (size_t)bcol * DIN + srcOff;

    // fragment read offsets (swizzled)
    const int aRow = (wm * 64 + l16) * 64;           // A region elem base
    const int bRow = 16384 + (wn * 64 + l16) * 64;   // B region elem base
    const int xr   = (l16 & 7) * 8;
    const int kc0  = (lk * 8) ^ xr;
    const int kc1  = (32 + lk * 8) ^ xr;

#define STAGE_A0(sl, k0) do { \
    const unsigned short* g_ = Abase + (k0); \
    unsigned short* d_ = lds + (sl) * SLOT_E + t * 8; \
    gl_lds16(g_, d_); gl_lds16(g_ + 64 * DIN, d_ + 4096); } while (0)

#define STAGE_A1(sl, k0) do { \
    const unsigned short* g_ = Abase + 128 * DIN + (k0); \
    unsigned short* d_ = lds + (sl) * SLOT_E + 8192 + t * 8; \
    gl_lds16(g_, d_); gl_lds16(g_ + 64 * DIN, d_ + 4096); } while (0)

#define STAGE_B(sl, k0, e) do { \
    const unsigned short* g_ = Bbase0 + (size_t)(e) * DEXP * DIN + (k0); \
    unsigned short* d_ = lds + (sl) * SLOT_E + 16384 + t * 8; \
    gl_lds16(g_, d_); gl_lds16(g_ + 64 * DIN, d_ + 4096); } while (0)

#define MFMA8(m0_, n0_) do { \
    __builtin_amdgcn_s_setprio(1); \
    acc[m0_][n0_]     = __builtin_amdgcn_mfma_f32_16x16x32_bf16(a[m0_][0],   bb[n0_][0],   acc[m0_][n0_],   0,0,0); \
    acc[m0_][n0_+1]   = __builtin_amdgcn_mfma_f32_16x16x32_bf16(a[m0_][0],   bb[n0_+1][0], acc[m0_][n0_+1], 0,0,0); \
    acc[m0_+1][n0_]   = __builtin_amdgcn_mfma_f32_16x16x32_bf16(a[m0_+1][0], bb[n0_][0],   acc[m0_+1][n0_], 0,0,0); \
    acc[m0_+1][n0_+1] = __builtin_amdgcn_mfma_f32_16x16x32_bf16(a[m0_+1][0], bb[n0_+1][0], acc[m0_+1][n0_+1],0,0,0); \
    acc[m0_][n0_]     = __builtin_amdgcn_mfma_f32_16x16x32_bf16(a[m0_][1],   bb[n0_][1],   acc[m0_][n0_],   0,0,0); \
    acc[m0_][n0_+1]   = __builtin_amdgcn_mfma_f32_16x16x32_bf16(a[m0_][1],   bb[n0_+1][1], acc[m0_][n0_+1], 0,0,0); \
    acc[m0_+1][n0_]   = __builtin_amdgcn_mfma_f32_16x16x32_bf16(a[m0_+1][1], bb[n0_][1],   acc[m0_+1][n0_], 0,0,0); \
    acc[m0_+1][n0_+1] = __builtin_amdgcn_mfma_f32_16x16x32_bf16(a[m0_+1][1], bb[n0_+1][1], acc[m0_+1][n0_+1],0,0,0); \
    __builtin_amdgcn_s_setprio(0); } while (0)

    f32x4 acc[4][4] = {};

    // prologue: stage tiles 0 and 1
    STAGE_A0(0, 0);  STAGE_A1(0, 0);  STAGE_B(0, 0, 0);
    STAGE_A0(1, 64); STAGE_A1(1, 64); STAGE_B(1, 64, 0);
    asm volatile("s_waitcnt vmcnt(6)" ::: "memory");   // tile 0 ready; tile 1 in flight
    __builtin_amdgcn_s_barrier();

    for (int T = 0; T < NT; ++T) {
        const int sl = T % 3;
        const unsigned short* L = lds + sl * SLOT_E;
        const int doSt = (T <= NT - 3);
        const int Ts = T + 2;
        const int sls = Ts % 3;
        const int k0s = (Ts & (TPE - 1)) * BK;
        const int es  = Ts >> 4;

        bf16x8 a[4][2], bb[4][2];

        // ---- phase 1: read a[0..1], b[0..1]; stage A0(T+2); MFMA q0 ----
        a[0][0]  = *(const bf16x8*)(L + aRow + kc0);
        a[0][1]  = *(const bf16x8*)(L + aRow + kc1);
        a[1][0]  = *(const bf16x8*)(L + aRow + 1024 + kc0);
        a[1][1]  = *(const bf16x8*)(L + aRow + 1024 + kc1);
        bb[0][0] = *(const bf16x8*)(L + bRow + kc0);
        bb[0][1] = *(const bf16x8*)(L + bRow + kc1);
        bb[1][0] = *(const bf16x8*)(L + bRow + 1024 + kc0);
        bb[1][1] = *(const bf16x8*)(L + bRow + 1024 + kc1);
        if (doSt) STAGE_A0(sls, k0s);
        __builtin_amdgcn_s_barrier();
        MFMA8(0, 0);
        __builtin_amdgcn_s_barrier();

        // ---- phase 2: read b[2..3]; stage A1(T+2); MFMA q1 ----
        bb[2][0] = *(const bf16x8*)(L + bRow + 2048 + kc0);
        bb[2][1] = *(const bf16x8*)(L + bRow + 2048 + kc1);
        bb[3][0] = *(const bf16x8*)(L + bRow + 3072 + kc0);
        bb[3][1] = *(const bf16x8*)(L + bRow + 3072 + kc1);
        if (doSt) STAGE_A1(sls, k0s);
        __builtin_amdgcn_s_barrier();
        MFMA8(0, 2);
        __builtin_amdgcn_s_barrier();

        // ---- phase 3: read a[2..3]; stage B(T+2); MFMA q2 ----
        a[2][0] = *(const bf16x8*)(L + aRow + 2048 + kc0);
        a[2][1] = *(const bf16x8*)(L + aRow + 2048 + kc1);
        a[3][0] = *(const bf16x8*)(L + aRow + 3072 + kc0);
        a[3][1] = *(const bf16x8*)(L + aRow + 3072 + kc1);
        if (doSt) STAGE_B(sls, k0s, es);
        __builtin_amdgcn_s_barrier();
        MFMA8(2, 0);
        __builtin_amdgcn_s_barrier();

        // ---- phase 4: counted wait (T+1 ready, T+2 in flight); MFMA q3 ----
        if (doSt) { asm volatile("s_waitcnt vmcnt(6)" ::: "memory"); }
        else      { asm volatile("s_waitcnt vmcnt(0)" ::: "memory"); }
        __builtin_amdgcn_s_barrier();
        MFMA8(2, 2);
        __builtin_amdgcn_s_barrier();

        // ---- fused per-expert epilogue: out RMW (each lane owns its elements) ----
        if ((T & (TPE - 1)) == (TPE - 1)) {
            const int e = T >> 4;
            float bias[4];
            #pragma unroll
            for (int nj = 0; nj < 4; ++nj)
                bias[nj] = be[(size_t)e * DEXP + bcol + wn * 64 + nj * 16 + l16];
            #pragma unroll
            for (int mi = 0; mi < 4; ++mi) {
                #pragma unroll
                for (int r = 0; r < 4; ++r) {
                    const int row = brow + wm * 64 + mi * 16 + lk * 4 + r;
                    const float g = gate[(size_t)row * NEXP + e];
                    float* op = out + (size_t)row * DEXP + bcol + wn * 64 + l16;
                    #pragma unroll
                    for (int nj = 0; nj < 4; ++nj) {
                        float v = g * fmaxf(acc[mi][nj][r] + bias[nj], 0.f);
                        if (e) v += op[nj * 16];
                        op[nj * 16] = v;
                    }
                }
            }
            #pragma unroll
            for (int mi = 0; mi < 4; ++mi)
                #pragma unroll
                for (int nj = 0; nj < 4; ++nj)
                    acc[mi][nj] = (f32x4){0.f, 0.f, 0.f, 0.f};
        }
    }
#undef STAGE_A0
#undef STAGE_A1
#undef STAGE_B
#undef MFMA8
}

extern "C" void kernel_launch(void* const* d_in, const int* in_sizes, int n_in,
                              void* d_out, int out_size, void* d_ws, size_t ws_size,
                              hipStream_t stream) {
    const float* x  = (const float*)d_in[0];
    const float* We = (const float*)d_in[1];
    const float* be = (const float*)d_in[2];
    const float* Wg = (const float*)d_in[3];
    const float* bg = (const float*)d_in[4];
    float* out = (float*)d_out;

    unsigned short* Xb = (unsigned short*)d_ws;                    // 16 MiB bf16 x
    unsigned short* Wt = Xb + (size_t)M_TOT * DIN;                 // 16 MiB bf16 We^T
    float* gate = (float*)(Wt + (size_t)NEXP * DEXP * DIN);        // 256 KiB fp32 gate

    hipLaunchKernelGGL(cvt_x_k, dim3(2048), dim3(256), 0, stream, x, Xb, M_TOT * DIN / 8);
    hipLaunchKernelGGL(cvt_w_k, dim3(16, 16, 8), dim3(256), 0, stream, We, Wt);
    hipLaunchKernelGGL(gate_k, dim3(512), dim3(256), 0, stream, x, Wg, bg, gate);
    hipLaunchKernelGGL(moe_k, dim3((M_TOT / BM) * (DEXP / BN)), dim3(512), 0, stream,
                       Xb, Wt, gate, be, out);
}

// Round 4
// 168.747 us; speedup vs baseline: 1.7202x; 1.7202x over previous
//
#include <hip/hip_runtime.h>
#include <hip/hip_bf16.h>
#include <stdint.h>

#define M_TOT 8192
#define DIN   1024
#define DEXP  1024
#define NEXP  8

#define BM 128
#define BN 256
#define BK 64
#define NT 128            // 8 experts * 16 K-tiles
#define TPE 16
#define SLOT_E 24576      // elems per LDS slot: A 8192 + B 16384 (48 KiB)
#define EXPSZ (DEXP * DIN)

typedef __attribute__((ext_vector_type(8))) short bf16x8;
typedef __attribute__((ext_vector_type(4))) float f32x4;
typedef __attribute__((ext_vector_type(8))) unsigned short us8;

typedef __attribute__((address_space(1))) void* as1vp;
typedef __attribute__((address_space(3))) void* as3vp;

__device__ __forceinline__ unsigned short f2bf(float f) {
    union { float f; unsigned u; } v; v.f = f;
    return (unsigned short)((v.u + 0x7fffu + ((v.u >> 16) & 1u)) >> 16);
}

__device__ __forceinline__ void gl_lds16(const unsigned short* g, unsigned short* l) {
    __builtin_amdgcn_global_load_lds((as1vp)g, (as3vp)l, 16, 0, 0);
}

#define MFMA(va, vb, vc) __builtin_amdgcn_mfma_f32_16x16x32_bf16(va, vb, vc, 0, 0, 0)

// ---------------- x fp32 -> bf16 ----------------
__global__ __launch_bounds__(256) void cvt_x_k(const float* __restrict__ in,
                                               unsigned short* __restrict__ out, int n8) {
    int i = blockIdx.x * 256 + threadIdx.x;
    int stride = gridDim.x * 256;
    for (; i < n8; i += stride) {
        const float4* p = (const float4*)in + (size_t)i * 2;
        float4 a = p[0], b = p[1];
        us8 o;
        o[0] = f2bf(a.x); o[1] = f2bf(a.y); o[2] = f2bf(a.z); o[3] = f2bf(a.w);
        o[4] = f2bf(b.x); o[5] = f2bf(b.y); o[6] = f2bf(b.z); o[7] = f2bf(b.w);
        *(us8*)(out + (size_t)i * 8) = o;
    }
}

// ------- We (n, din, dexp) fp32 -> Wt (n, dexp, din) bf16, tiled transpose -------
__global__ __launch_bounds__(256) void cvt_w_k(const float* __restrict__ We,
                                               unsigned short* __restrict__ Wt) {
    __shared__ float tile[64][65];
    int n  = blockIdx.z;
    int k0 = blockIdx.y * 64;
    int j0 = blockIdx.x * 64;
    int t  = threadIdx.x;
    int tr = t >> 6, tc = t & 63;
    const float* src = We + (size_t)n * DIN * DEXP;
    #pragma unroll
    for (int rr = 0; rr < 16; ++rr) {
        int r = rr * 4 + tr;
        tile[r][tc] = src[(size_t)(k0 + r) * DEXP + j0 + tc];
    }
    __syncthreads();
    unsigned short* dst = Wt + (size_t)n * DEXP * DIN;
    #pragma unroll
    for (int rr = 0; rr < 16; ++rr) {
        int r = rr * 4 + tr;
        dst[(size_t)(j0 + r) * DIN + k0 + tc] = f2bf(tile[tc][r]);
    }
}

// ---------------- gate = softmax(x @ Wg + bg) ----------------
__global__ __launch_bounds__(256) void gate_k(const float* __restrict__ x,
                                              const float* __restrict__ Wg,
                                              const float* __restrict__ bg,
                                              float* __restrict__ gate) {
    __shared__ float wgt[NEXP][DIN];
    int t = threadIdx.x;
    for (int idx = t; idx < DIN * NEXP; idx += 256)
        wgt[idx & 7][idx >> 3] = Wg[idx];
    __syncthreads();
    int wid = t >> 6, lane = t & 63;
    for (int m = blockIdx.x * 4 + wid; m < M_TOT; m += gridDim.x * 4) {
        const float* xr = x + (size_t)m * DIN;
        float acc[NEXP];
        #pragma unroll
        for (int n = 0; n < NEXP; ++n) acc[n] = 0.f;
        for (int i = 0; i < DIN / 64; ++i) {
            int d = i * 64 + lane;
            float xv = xr[d];
            #pragma unroll
            for (int n = 0; n < NEXP; ++n) acc[n] = fmaf(xv, wgt[n][d], acc[n]);
        }
        #pragma unroll
        for (int n = 0; n < NEXP; ++n) {
            #pragma unroll
            for (int off = 32; off; off >>= 1) acc[n] += __shfl_xor(acc[n], off);
            acc[n] += bg[n];
        }
        float mx = acc[0];
        #pragma unroll
        for (int n = 1; n < NEXP; ++n) mx = fmaxf(mx, acc[n]);
        float s = 0.f, e[NEXP];
        #pragma unroll
        for (int n = 0; n < NEXP; ++n) { e[n] = __expf(acc[n] - mx); s += e[n]; }
        float inv = 1.f / s;
        if (lane < NEXP) gate[(size_t)m * NEXP + lane] = e[lane] * inv;
    }
}

// ---------------- fused MoE GEMM: 2-phase/K-tile counted-vmcnt pipeline ----------------
// out[m,j] = sum_e gate[m,e] * relu( (Xb @ Wt[e]^T)[m,j] + be[e,j] )
__global__ __launch_bounds__(512, 2) void moe_k(const unsigned short* __restrict__ Xb,
                                                const unsigned short* __restrict__ Wt,
                                                const float* __restrict__ gate,
                                                const float* __restrict__ be,
                                                float* __restrict__ out) {
    // 3 rotating slots, each: A [128][64] (elems 0..8191), B [256][64] (8192..24575)
    __shared__ __align__(16) unsigned short lds[3 * SLOT_E];   // 144 KiB
    __shared__ float gateL[BM * NEXP];                          // 4 KiB
    __shared__ float biasL[NEXP * BN];                          // 8 KiB

    const int t    = threadIdx.x;
    const int lane = t & 63;
    const int wv   = t >> 6;
    const int wm   = wv >> 2;           // 0..1 (M)
    const int wn   = wv & 3;            // 0..3 (N)
    const int l16  = lane & 15;
    const int lk   = lane >> 4;

    // bijective XCD swizzle; each 32-block XCD chunk = 8 M-tiles x 4 N-tiles
    const int b    = blockIdx.x;
    const int lg   = (b & 7) * 32 + (b >> 3);
    const int brow = (lg >> 2) * BM;    // 64 M-tiles
    const int bcol = (lg & 3) * BN;     // 4 N-tiles

    // staging: thread t covers row r1 = t>>3, phys col-group t&7 (XOR-preswizzled src)
    const int r1     = t >> 3;
    const int srcOff = r1 * DIN + (((t & 7) ^ (r1 & 7)) * 8);
    const unsigned short* gA = Xb + (size_t)brow * DIN;
    const unsigned short* gB = Wt + (size_t)bcol * DIN;

    // fragment read offsets (swizzled): col group g at row r lives at (g ^ (r&7))*8
    const int xr    = (l16 & 7) * 8;
    const int kc0   = (lk * 8) ^ xr;
    const int kc1   = (32 + lk * 8) ^ xr;
    const int aBase = (wm * 64 + l16) * 64;          // + mi*1024
    const int bBase = 8192 + (wn * 64 + l16) * 64;   // + ni*1024

#define STAGE_A(sl_, k0_) do { \
    const unsigned short* g_ = gA + (k0_) + srcOff; \
    unsigned short* d_ = (unsigned short*)lds + (sl_) * SLOT_E + t * 8; \
    gl_lds16(g_, d_); gl_lds16(g_ + 64 * DIN, d_ + 4096); } while (0)
#define STAGE_B0(sl_, e_, k0_) do { \
    const unsigned short* g_ = gB + (size_t)(e_) * EXPSZ + (k0_) + srcOff; \
    unsigned short* d_ = (unsigned short*)lds + (sl_) * SLOT_E + 8192 + t * 8; \
    gl_lds16(g_, d_); gl_lds16(g_ + 64 * DIN, d_ + 4096); } while (0)
#define STAGE_B1(sl_, e_, k0_) do { \
    const unsigned short* g_ = gB + (size_t)(e_) * EXPSZ + 128 * DIN + (k0_) + srcOff; \
    unsigned short* d_ = (unsigned short*)lds + (sl_) * SLOT_E + 16384 + t * 8; \
    gl_lds16(g_, d_); gl_lds16(g_ + 64 * DIN, d_ + 4096); } while (0)

    f32x4 acc_e[4][4] = {};
    f32x4 acc_o[4][4] = {};

    // ---- prologue: gate+bias -> LDS (VMEM retired before stages via ds_write deps) ----
    {
        const float* gp = gate + (size_t)brow * NEXP;
        gateL[t]       = gp[t];
        gateL[t + 512] = gp[t + 512];
        #pragma unroll
        for (int i = 0; i < 4; ++i) {
            int idx = t + i * 512;
            biasL[idx] = be[(size_t)(idx >> 8) * DEXP + bcol + (idx & 255)];
        }
    }
    // stage tiles 0,1 into slots 0,1
    STAGE_A(0, 0);  STAGE_B0(0, 0, 0);  STAGE_B1(0, 0, 0);
    STAGE_A(1, 64); STAGE_B0(1, 0, 64); STAGE_B1(1, 0, 64);
    asm volatile("s_waitcnt vmcnt(6)" ::: "memory");   // tile 0 landed; tile 1 in flight
    asm volatile("s_waitcnt lgkmcnt(0)" ::: "memory"); // gate/bias ds_writes committed
    __builtin_amdgcn_s_barrier();

    int sl = 0, sl2 = 2;
    for (int T = 0; T < NT; ++T) {
        const unsigned short* L = lds + sl * SLOT_E;
        const int e2 = (T + 2) >> 4;
        const int k2 = ((T + 2) & (TPE - 1)) * BK;
        const bool doSt = (T < NT - 2);

        bf16x8 a0[4], b0[4], a1[4], b1[4];

        // ===== phase 1: read ks=0 frags; stage A,B0(T+2); MFMA ks=0 (16) =====
        #pragma unroll
        for (int mi = 0; mi < 4; ++mi) a0[mi] = *(const bf16x8*)(L + aBase + mi * 1024 + kc0);
        #pragma unroll
        for (int ni = 0; ni < 4; ++ni) b0[ni] = *(const bf16x8*)(L + bBase + ni * 1024 + kc0);
        if (doSt) { STAGE_A(sl2, k2); STAGE_B0(sl2, e2, k2); }
        __builtin_amdgcn_s_barrier();
        asm volatile("s_waitcnt lgkmcnt(0)" ::: "memory");
        __builtin_amdgcn_sched_barrier(0);
        __builtin_amdgcn_s_setprio(1);
        #pragma unroll
        for (int mi = 0; mi < 4; ++mi)
            #pragma unroll
            for (int ni = 0; ni < 4; ++ni)
                acc_e[mi][ni] = MFMA(a0[mi], b0[ni], acc_e[mi][ni]);
        __builtin_amdgcn_s_setprio(0);
        __builtin_amdgcn_s_barrier();

        // ===== phase 2: read ks=1 frags; stage B1(T+2); counted vmcnt; MFMA ks=1 =====
        #pragma unroll
        for (int mi = 0; mi < 4; ++mi) a1[mi] = *(const bf16x8*)(L + aBase + mi * 1024 + kc1);
        #pragma unroll
        for (int ni = 0; ni < 4; ++ni) b1[ni] = *(const bf16x8*)(L + bBase + ni * 1024 + kc1);
        if (doSt) {
            STAGE_B1(sl2, e2, k2);
            asm volatile("s_waitcnt vmcnt(6)" ::: "memory");  // tile T+1 landed; T+2 in flight
        } else {
            asm volatile("s_waitcnt vmcnt(0)" ::: "memory");  // tail drain
        }
        __builtin_amdgcn_s_barrier();
        asm volatile("s_waitcnt lgkmcnt(0)" ::: "memory");
        __builtin_amdgcn_sched_barrier(0);
        __builtin_amdgcn_s_setprio(1);
        #pragma unroll
        for (int mi = 0; mi < 4; ++mi)
            #pragma unroll
            for (int ni = 0; ni < 4; ++ni)
                acc_e[mi][ni] = MFMA(a1[mi], b1[ni], acc_e[mi][ni]);
        __builtin_amdgcn_s_setprio(0);
        __builtin_amdgcn_s_barrier();

        // ===== fused per-expert epilogue (LDS + registers only) =====
        if ((T & (TPE - 1)) == (TPE - 1)) {
            const int e = T >> 4;
            float bias[4];
            #pragma unroll
            for (int ni = 0; ni < 4; ++ni)
                bias[ni] = biasL[e * BN + wn * 64 + ni * 16 + l16];
            #pragma unroll
            for (int mi = 0; mi < 4; ++mi) {
                #pragma unroll
                for (int r = 0; r < 4; ++r) {
                    const int rl = wm * 64 + mi * 16 + lk * 4 + r;
                    const float g = gateL[rl * NEXP + e];
                    #pragma unroll
                    for (int ni = 0; ni < 4; ++ni)
                        acc_o[mi][ni][r] += g * fmaxf(acc_e[mi][ni][r] + bias[ni], 0.f);
                }
            }
            #pragma unroll
            for (int mi = 0; mi < 4; ++mi)
                #pragma unroll
                for (int ni = 0; ni < 4; ++ni)
                    acc_e[mi][ni] = (f32x4){0.f, 0.f, 0.f, 0.f};
        }

        sl  = (sl  == 2) ? 0 : sl  + 1;
        sl2 = (sl2 == 2) ? 0 : sl2 + 1;
    }

    // final store (once)
    #pragma unroll
    for (int mi = 0; mi < 4; ++mi) {
        #pragma unroll
        for (int r = 0; r < 4; ++r) {
            const int row = brow + wm * 64 + mi * 16 + lk * 4 + r;
            float* op = out + (size_t)row * DEXP + bcol + wn * 64 + l16;
            #pragma unroll
            for (int ni = 0; ni < 4; ++ni) op[ni * 16] = acc_o[mi][ni][r];
        }
    }
#undef STAGE_A
#undef STAGE_B0
#undef STAGE_B1
}

extern "C" void kernel_launch(void* const* d_in, const int* in_sizes, int n_in,
                              void* d_out, int out_size, void* d_ws, size_t ws_size,
                              hipStream_t stream) {
    const float* x  = (const float*)d_in[0];
    const float* We = (const float*)d_in[1];
    const float* be = (const float*)d_in[2];
    const float* Wg = (const float*)d_in[3];
    const float* bg = (const float*)d_in[4];
    float* out = (float*)d_out;

    unsigned short* Xb = (unsigned short*)d_ws;                    // 16 MiB bf16 x
    unsigned short* Wt = Xb + (size_t)M_TOT * DIN;                 // 16 MiB bf16 We^T
    float* gate = (float*)(Wt + (size_t)NEXP * DEXP * DIN);        // 256 KiB fp32 gate

    hipLaunchKernelGGL(cvt_x_k, dim3(2048), dim3(256), 0, stream, x, Xb, M_TOT * DIN / 8);
    hipLaunchKernelGGL(cvt_w_k, dim3(16, 16, 8), dim3(256), 0, stream, We, Wt);
    hipLaunchKernelGGL(gate_k, dim3(512), dim3(256), 0, stream, x, Wg, bg, gate);
    hipLaunchKernelGGL(moe_k, dim3((M_TOT / BM) * (DEXP / BN)), dim3(512), 0, stream,
                       Xb, Wt, gate, be, out);
}

// Round 5
// 163.919 us; speedup vs baseline: 1.7709x; 1.0295x over previous
//
#include <hip/hip_runtime.h>
#include <hip/hip_bf16.h>
#include <stdint.h>

#define M_TOT 8192
#define DIN   1024
#define DEXP  1024
#define NEXP  8

#define BM 256
#define BN 128
#define BK 32
#define NT 128            // 4 expert-pairs * 32 K-tiles
#define KPP 32            // K-tiles per pair
#define SLOT_E 16384      // elems per LDS slot: A 8192 + B0 4096 + B1 4096 (32 KiB)
#define EXPSZ (DEXP * DIN)

typedef __attribute__((ext_vector_type(8))) short bf16x8;
typedef __attribute__((ext_vector_type(4))) float f32x4;
typedef __attribute__((ext_vector_type(8))) unsigned short us8;

typedef __attribute__((address_space(1))) void* as1vp;
typedef __attribute__((address_space(3))) void* as3vp;

__device__ __forceinline__ unsigned short f2bf(float f) {
    union { float f; unsigned u; } v; v.f = f;
    return (unsigned short)((v.u + 0x7fffu + ((v.u >> 16) & 1u)) >> 16);
}

__device__ __forceinline__ void gl_lds16(const unsigned short* g, unsigned short* l) {
    __builtin_amdgcn_global_load_lds((as1vp)g, (as3vp)l, 16, 0, 0);
}

#define MFMA(va, vb, vc) __builtin_amdgcn_mfma_f32_16x16x32_bf16(va, vb, vc, 0, 0, 0)

// ---------------- x fp32 -> bf16 ----------------
__global__ __launch_bounds__(256) void cvt_x_k(const float* __restrict__ in,
                                               unsigned short* __restrict__ out, int n8) {
    int i = blockIdx.x * 256 + threadIdx.x;
    int stride = gridDim.x * 256;
    for (; i < n8; i += stride) {
        const float4* p = (const float4*)in + (size_t)i * 2;
        float4 a = p[0], b = p[1];
        us8 o;
        o[0] = f2bf(a.x); o[1] = f2bf(a.y); o[2] = f2bf(a.z); o[3] = f2bf(a.w);
        o[4] = f2bf(b.x); o[5] = f2bf(b.y); o[6] = f2bf(b.z); o[7] = f2bf(b.w);
        *(us8*)(out + (size_t)i * 8) = o;
    }
}

// ------- We (n, din, dexp) fp32 -> Wt (n, dexp, din) bf16, tiled transpose -------
__global__ __launch_bounds__(256) void cvt_w_k(const float* __restrict__ We,
                                               unsigned short* __restrict__ Wt) {
    __shared__ float tile[64][65];
    int n  = blockIdx.z;
    int k0 = blockIdx.y * 64;
    int j0 = blockIdx.x * 64;
    int t  = threadIdx.x;
    int tr = t >> 6, tc = t & 63;
    const float* src = We + (size_t)n * DIN * DEXP;
    #pragma unroll
    for (int rr = 0; rr < 16; ++rr) {
        int r = rr * 4 + tr;
        tile[r][tc] = src[(size_t)(k0 + r) * DEXP + j0 + tc];
    }
    __syncthreads();
    unsigned short* dst = Wt + (size_t)n * DEXP * DIN;
    #pragma unroll
    for (int rr = 0; rr < 16; ++rr) {
        int r = rr * 4 + tr;
        dst[(size_t)(j0 + r) * DIN + k0 + tc] = f2bf(tile[tc][r]);
    }
}

// ---------------- gate = softmax(x @ Wg + bg) ----------------
__global__ __launch_bounds__(256) void gate_k(const float* __restrict__ x,
                                              const float* __restrict__ Wg,
                                              const float* __restrict__ bg,
                                              float* __restrict__ gate) {
    __shared__ float wgt[NEXP][DIN];
    int t = threadIdx.x;
    for (int idx = t; idx < DIN * NEXP; idx += 256)
        wgt[idx & 7][idx >> 3] = Wg[idx];
    __syncthreads();
    int wid = t >> 6, lane = t & 63;
    for (int m = blockIdx.x * 4 + wid; m < M_TOT; m += gridDim.x * 4) {
        const float* xr = x + (size_t)m * DIN;
        float acc[NEXP];
        #pragma unroll
        for (int n = 0; n < NEXP; ++n) acc[n] = 0.f;
        for (int i = 0; i < DIN / 64; ++i) {
            int d = i * 64 + lane;
            float xv = xr[d];
            #pragma unroll
            for (int n = 0; n < NEXP; ++n) acc[n] = fmaf(xv, wgt[n][d], acc[n]);
        }
        #pragma unroll
        for (int n = 0; n < NEXP; ++n) {
            #pragma unroll
            for (int off = 32; off; off >>= 1) acc[n] += __shfl_xor(acc[n], off);
            acc[n] += bg[n];
        }
        float mx = acc[0];
        #pragma unroll
        for (int n = 1; n < NEXP; ++n) mx = fmaxf(mx, acc[n]);
        float s = 0.f, e[NEXP];
        #pragma unroll
        for (int n = 0; n < NEXP; ++n) { e[n] = __expf(acc[n] - mx); s += e[n]; }
        float inv = 1.f / s;
        if (lane < NEXP) gate[(size_t)m * NEXP + lane] = e[lane] * inv;
    }
}

// ---------- fused MoE GEMM: expert-pair, BK=32, counted-vmcnt 2-phase pipeline ----------
// out[m,j] = sum_e gate[m,e] * relu( (Xb @ Wt[e]^T)[m,j] + be[e,j] )
__global__ __launch_bounds__(512, 2) void moe_k(const unsigned short* __restrict__ Xb,
                                                const unsigned short* __restrict__ Wt,
                                                const float* __restrict__ gate,
                                                const float* __restrict__ be,
                                                float* __restrict__ out) {
    // 3 rotating slots: A [256][32] (0..8191), B0 [128][32] (8192..12287), B1 (12288..16383)
    __shared__ __align__(16) unsigned short lds[3 * SLOT_E];   // 96 KiB
    __shared__ float gateL[BM * NEXP];                          // 8 KiB
    __shared__ float biasL[NEXP * BN];                          // 4 KiB

    const int t    = threadIdx.x;
    const int lane = t & 63;
    const int wv   = t >> 6;
    const int wm   = wv >> 1;           // 0..3 (M)
    const int wn   = wv & 1;            // 0..1 (N)
    const int l16  = lane & 15;
    const int lk   = lane >> 4;

    // bijective XCD swizzle; per-XCD chunk = 4 M-tiles x 8 N-tiles
    const int b    = blockIdx.x;
    const int lg   = (b & 7) * 32 + (b >> 3);
    const int brow = (lg >> 3) * BM;    // 32 M-tiles
    const int bcol = (lg & 7) * BN;     // 8 N-tiles

    // staging: thread t -> row = t>>2 (64B rows), chunk (t&3), XOR-preswizzled source
    const int sA = (t >> 2) * DIN + ((((t & 3) ^ ((t >> 2) & 3))) * 8);
    const unsigned short* gA = Xb + (size_t)brow * DIN;
    const unsigned short* gB = Wt + (size_t)bcol * DIN;

    // fragment read offsets (swizzled): chunk' = lk ^ (l16&3)
    const int xc    = ((lk ^ (l16 & 3)) * 8);
    const int aOff  = (wm * 64 + l16) * 32 + xc;           // + mi*512
    const int bOff  = 8192 + (wn * 64 + l16) * 32 + xc;    // + ni*512 ; B1: +4096

#define STAGE_A(sl_, k0_) do { \
    const unsigned short* g_ = gA + (k0_) + sA; \
    unsigned short* d_ = (unsigned short*)lds + (sl_) * SLOT_E + t * 8; \
    gl_lds16(g_, d_); gl_lds16(g_ + 128 * DIN, d_ + 4096); } while (0)
#define STAGE_B0(sl_, e_, k0_) do { \
    gl_lds16(gB + (size_t)(e_) * EXPSZ + (k0_) + sA, \
             (unsigned short*)lds + (sl_) * SLOT_E + 8192 + t * 8); } while (0)
#define STAGE_B1(sl_, e_, k0_) do { \
    gl_lds16(gB + (size_t)(e_) * EXPSZ + (k0_) + sA, \
             (unsigned short*)lds + (sl_) * SLOT_E + 12288 + t * 8); } while (0)

    f32x4 acc_e0[4][4] = {};
    f32x4 acc_e1[4][4] = {};
    f32x4 acc_o[4][4]  = {};

    // ---- prologue: gate+bias -> LDS; stage iters 0,1 into slots 0,1 ----
    {
        const float* gp = gate + (size_t)brow * NEXP;     // 2048 floats
        ((float4*)gateL)[t] = ((const float4*)gp)[t];
        if (t < 256)                                       // 1024 floats
            ((float4*)biasL)[t] =
                *(const float4*)(be + (size_t)(t >> 5) * DEXP + bcol + (t & 31) * 4);
    }
    STAGE_A(0, 0);  STAGE_B0(0, 0, 0);  STAGE_B1(0, 1, 0);
    STAGE_A(1, 32); STAGE_B0(1, 0, 32); STAGE_B1(1, 1, 32);
    asm volatile("s_waitcnt vmcnt(4)" ::: "memory");   // iter 0 landed; iter 1 in flight
    asm volatile("s_waitcnt lgkmcnt(0)" ::: "memory"); // gate/bias ds_writes committed
    __builtin_amdgcn_s_barrier();

    int sl = 0, sl2 = 2;
    for (int T = 0; T < NT; ++T) {
        const unsigned short* L = lds + sl * SLOT_E;
        const int p2  = (T + 2) >> 5;
        const int k2  = ((T + 2) & (KPP - 1)) * BK;
        const bool doSt = (T < NT - 2);

        bf16x8 a[4], b0[4], b1[4];

        // ===== phase 1: read A + B0 frags; stage A(T+2); MFMA -> acc_e0 =====
        #pragma unroll
        for (int mi = 0; mi < 4; ++mi) a[mi]  = *(const bf16x8*)(L + aOff + mi * 512);
        #pragma unroll
        for (int ni = 0; ni < 4; ++ni) b0[ni] = *(const bf16x8*)(L + bOff + ni * 512);
        if (doSt) STAGE_A(sl2, k2);
        __builtin_amdgcn_s_barrier();
        asm volatile("s_waitcnt lgkmcnt(0)" ::: "memory");
        __builtin_amdgcn_sched_barrier(0);
        __builtin_amdgcn_s_setprio(1);
        #pragma unroll
        for (int mi = 0; mi < 4; ++mi)
            #pragma unroll
            for (int ni = 0; ni < 4; ++ni)
                acc_e0[mi][ni] = MFMA(a[mi], b0[ni], acc_e0[mi][ni]);
        __builtin_amdgcn_s_setprio(0);
        __builtin_amdgcn_s_barrier();

        // ===== phase 2: read B1 frags; stage B0,B1(T+2); vmcnt(4); MFMA -> acc_e1 =====
        #pragma unroll
        for (int ni = 0; ni < 4; ++ni) b1[ni] = *(const bf16x8*)(L + bOff + 4096 + ni * 512);
        if (doSt) {
            STAGE_B0(sl2, p2 * 2, k2);
            STAGE_B1(sl2, p2 * 2 + 1, k2);
            asm volatile("s_waitcnt vmcnt(4)" ::: "memory");  // iter T+1 landed; T+2 in flight
        } else {
            asm volatile("s_waitcnt vmcnt(0)" ::: "memory");  // tail drain
        }
        __builtin_amdgcn_s_barrier();
        asm volatile("s_waitcnt lgkmcnt(0)" ::: "memory");
        __builtin_amdgcn_sched_barrier(0);
        __builtin_amdgcn_s_setprio(1);
        #pragma unroll
        for (int mi = 0; mi < 4; ++mi)
            #pragma unroll
            for (int ni = 0; ni < 4; ++ni)
                acc_e1[mi][ni] = MFMA(a[mi], b1[ni], acc_e1[mi][ni]);
        __builtin_amdgcn_s_setprio(0);
        __builtin_amdgcn_s_barrier();

        // ===== fused pair epilogue (LDS broadcast + registers; no barriers) =====
        if ((T & (KPP - 1)) == (KPP - 1)) {
            const int e0 = (T >> 5) * 2, e1 = e0 + 1;
            float bi0[4], bi1[4];
            #pragma unroll
            for (int ni = 0; ni < 4; ++ni) {
                bi0[ni] = biasL[e0 * BN + wn * 64 + ni * 16 + l16];
                bi1[ni] = biasL[e1 * BN + wn * 64 + ni * 16 + l16];
            }
            #pragma unroll
            for (int mi = 0; mi < 4; ++mi) {
                #pragma unroll
                for (int r = 0; r < 4; ++r) {
                    const int rl = wm * 64 + mi * 16 + lk * 4 + r;
                    const float g0 = gateL[rl * NEXP + e0];
                    const float g1 = gateL[rl * NEXP + e1];
                    #pragma unroll
                    for (int ni = 0; ni < 4; ++ni) {
                        acc_o[mi][ni][r] += g0 * fmaxf(acc_e0[mi][ni][r] + bi0[ni], 0.f)
                                          + g1 * fmaxf(acc_e1[mi][ni][r] + bi1[ni], 0.f);
                    }
                }
            }
            #pragma unroll
            for (int mi = 0; mi < 4; ++mi)
                #pragma unroll
                for (int ni = 0; ni < 4; ++ni) {
                    acc_e0[mi][ni] = (f32x4){0.f, 0.f, 0.f, 0.f};
                    acc_e1[mi][ni] = (f32x4){0.f, 0.f, 0.f, 0.f};
                }
        }

        sl  = (sl  == 2) ? 0 : sl  + 1;
        sl2 = (sl2 == 2) ? 0 : sl2 + 1;
    }

    // final store (once)
    #pragma unroll
    for (int mi = 0; mi < 4; ++mi) {
        #pragma unroll
        for (int r = 0; r < 4; ++r) {
            const int row = brow + wm * 64 + mi * 16 + lk * 4 + r;
            float* op = out + (size_t)row * DEXP + bcol + wn * 64 + l16;
            #pragma unroll
            for (int ni = 0; ni < 4; ++ni) op[ni * 16] = acc_o[mi][ni][r];
        }
    }
#undef STAGE_A
#undef STAGE_B0
#undef STAGE_B1
}

extern "C" void kernel_launch(void* const* d_in, const int* in_sizes, int n_in,
                              void* d_out, int out_size, void* d_ws, size_t ws_size,
                              hipStream_t stream) {
    const float* x  = (const float*)d_in[0];
    const float* We = (const float*)d_in[1];
    const float* be = (const float*)d_in[2];
    const float* Wg = (const float*)d_in[3];
    const float* bg = (const float*)d_in[4];
    float* out = (float*)d_out;

    unsigned short* Xb = (unsigned short*)d_ws;                    // 16 MiB bf16 x
    unsigned short* Wt = Xb + (size_t)M_TOT * DIN;                 // 16 MiB bf16 We^T
    float* gate = (float*)(Wt + (size_t)NEXP * DEXP * DIN);        // 256 KiB fp32 gate

    hipLaunchKernelGGL(cvt_x_k, dim3(2048), dim3(256), 0, stream, x, Xb, M_TOT * DIN / 8);
    hipLaunchKernelGGL(cvt_w_k, dim3(16, 16, 8), dim3(256), 0, stream, We, Wt);
    hipLaunchKernelGGL(gate_k, dim3(512), dim3(256), 0, stream, x, Wg, bg, gate);
    hipLaunchKernelGGL(moe_k, dim3((M_TOT / BM) * (DEXP / BN)), dim3(512), 0, stream,
                       Xb, Wt, gate, be, out);
}